// Round 1
// baseline (1293.068 us; speedup 1.0000x reference)
//
#include <hip/hip_runtime.h>

typedef _Float16 f16x8 __attribute__((ext_vector_type(8)));
typedef float f32x4 __attribute__((ext_vector_type(4)));

#define DEV __device__ __forceinline__

struct alignas(16) H8 { _Float16 h[8]; };
struct alignas(8)  H4 { _Float16 h[4]; };

DEV f32x4 mfma16(f16x8 a, f16x8 b, f32x4 c) {
  return __builtin_amdgcn_mfma_f32_16x16x32_f16(a, b, c, 0, 0, 0);
}

// read 8 fp16 from 72-byte-stride bT layout (two b64 loads, 8B aligned)
DEV f16x8 frag_b36(const _Float16* b, int n, int kc) {
  const unsigned long long* p = (const unsigned long long*)(b + n*36 + kc*8);
  union { unsigned long long u[2]; f16x8 v; } r;
  r.u[0] = p[0]; r.u[1] = p[1];
  return r.v;
}

DEV float block_sum(float v, volatile float* red, int tid) {
  #pragma unroll
  for (int mm = 1; mm < 64; mm <<= 1) v += __shfl_xor(v, mm);
  if ((tid & 63) == 0) red[tid >> 6] = v;
  __syncthreads();
  return red[0] + red[1] + red[2] + red[3];
}

// ---------------- RMSNorm (input) -> fp16 hi/lo split ----------------
__global__ __launch_bounds__(256) void k_rmsnorm_split(
    const float* __restrict__ x, const float* __restrict__ w,
    _Float16* __restrict__ hi, _Float16* __restrict__ lo) {
  __shared__ float red[4];
  int row = blockIdx.x, tid = threadIdx.x;
  const float* xr = x + (size_t)row*2048 + tid*8;
  float xs[8];
  *(float4*)&xs[0] = *(const float4*)xr;
  *(float4*)&xs[4] = *(const float4*)(xr + 4);
  float ss = 0.f;
  #pragma unroll
  for (int j = 0; j < 8; ++j) ss += xs[j]*xs[j];
  float tot = block_sum(ss, red, tid);
  float sc = 1.0f / sqrtf(tot*(1.0f/2048.0f) + 1e-5f);
  const float* wr = w + tid*8;
  H8 ph, pl;
  #pragma unroll
  for (int j = 0; j < 8; ++j) {
    float o = xs[j]*sc*wr[j];
    _Float16 hh = (_Float16)o;
    ph.h[j] = hh; pl.h[j] = (_Float16)(o - (float)hh);
  }
  *(H8*)(hi + (size_t)row*2048 + tid*8) = ph;
  *(H8*)(lo + (size_t)row*2048 + tid*8) = pl;
}

// ---------------- dense split GEMM: C = A@B, A fp16-pair or f32, B f32 ----------------
// 3-term fp16x2 MFMA for ~f32 accuracy. BM=BN=128, BK=32, 4 waves.
template<int AMODE, bool RESID>
__global__ __launch_bounds__(256) void k_gemm(
    const void* __restrict__ Ahi, const void* __restrict__ Alo,
    const float* __restrict__ B, int N, int K,
    float* __restrict__ C,
    const float* __restrict__ resid_in, float* __restrict__ resid_out) {
  const int tid = threadIdx.x;
  const int l = tid & 63, w = tid >> 6;
  const int wm = w >> 1, wn = w & 1;
  const int row0 = blockIdx.y * 128, col0 = blockIdx.x * 128;

  __shared__ _Float16 aHi[128*32], aLo[128*32];
  __shared__ _Float16 bHi[128*36], bLo[128*36];

  f32x4 acc[4][4] = {};

  const int rS = tid >> 1, khalf = tid & 1;
  const int bn = tid & 127, bkg = tid >> 7;

  for (int k0 = 0; k0 < K; k0 += 32) {
    __syncthreads();
    { // stage A (chunk-XOR swizzled)
      int c0 = khalf*2;
      int d0 = rS*32 + ((c0    ) ^ (rS&3))*8;
      int d1 = rS*32 + ((c0 + 1) ^ (rS&3))*8;
      if constexpr (AMODE == 0) {
        const _Float16* ah = (const _Float16*)Ahi + (size_t)(row0 + rS)*K + k0 + khalf*16;
        const _Float16* al = (const _Float16*)Alo + (size_t)(row0 + rS)*K + k0 + khalf*16;
        *(H8*)&aHi[d0] = *(const H8*)ah;
        *(H8*)&aHi[d1] = *(const H8*)(ah + 8);
        *(H8*)&aLo[d0] = *(const H8*)al;
        *(H8*)&aLo[d1] = *(const H8*)(al + 8);
      } else {
        const float* af = (const float*)Ahi + (size_t)(row0 + rS)*K + k0 + khalf*16;
        H8 ph0, pl0, ph1, pl1;
        #pragma unroll
        for (int j = 0; j < 8; ++j) {
          float x0 = af[j], x1 = af[8 + j];
          _Float16 h0 = (_Float16)x0, h1 = (_Float16)x1;
          ph0.h[j] = h0; pl0.h[j] = (_Float16)(x0 - (float)h0);
          ph1.h[j] = h1; pl1.h[j] = (_Float16)(x1 - (float)h1);
        }
        *(H8*)&aHi[d0] = ph0; *(H8*)&aHi[d1] = ph1;
        *(H8*)&aLo[d0] = pl0; *(H8*)&aLo[d1] = pl1;
      }
    }
    { // stage B transposed + split
      const float* bp = B + (size_t)(k0 + bkg*16)*N + col0 + bn;
      float tv[16];
      #pragma unroll
      for (int i = 0; i < 16; ++i) tv[i] = bp[(size_t)i*N];
      #pragma unroll
      for (int q_ = 0; q_ < 4; ++q_) {
        H4 ph, pl;
        #pragma unroll
        for (int j = 0; j < 4; ++j) {
          float x = tv[q_*4 + j];
          _Float16 hh = (_Float16)x;
          ph.h[j] = hh; pl.h[j] = (_Float16)(x - (float)hh);
        }
        int ei = bn*36 + bkg*16 + q_*4;
        *(H4*)&bHi[ei] = ph;
        *(H4*)&bLo[ei] = pl;
      }
    }
    __syncthreads();
    { // compute
      const int kc = l >> 4;
      f16x8 ah[4], al4[4];
      #pragma unroll
      for (int m = 0; m < 4; ++m) {
        int mr = wm*64 + m*16 + (l & 15);
        int cc = (kc ^ (mr & 3))*8;
        ah[m]  = *(const f16x8*)&aHi[mr*32 + cc];
        al4[m] = *(const f16x8*)&aLo[mr*32 + cc];
      }
      #pragma unroll
      for (int n = 0; n < 4; ++n) {
        int nr = wn*64 + n*16 + (l & 15);
        f16x8 bh = frag_b36(bHi, nr, kc);
        f16x8 bl = frag_b36(bLo, nr, kc);
        #pragma unroll
        for (int m = 0; m < 4; ++m) {
          acc[m][n] = mfma16(ah[m],  bh, acc[m][n]);
          acc[m][n] = mfma16(ah[m],  bl, acc[m][n]);
          acc[m][n] = mfma16(al4[m], bh, acc[m][n]);
        }
      }
    }
  }
  #pragma unroll
  for (int m = 0; m < 4; ++m)
    #pragma unroll
    for (int n = 0; n < 4; ++n)
      #pragma unroll
      for (int r = 0; r < 4; ++r) {
        int row = row0 + wm*64 + m*16 + (l>>4)*4 + r;
        int col = col0 + wn*64 + n*16 + (l&15);
        float v = acc[m][n][r];
        if constexpr (RESID) {
          size_t idx = (size_t)row*2048 + col;
          v += resid_in[idx];
          resid_out[idx] = v;
        } else {
          C[(size_t)row*N + col] = v;
        }
      }
}

// ---------------- RoPE (neox, in-place, f32) ----------------
__global__ __launch_bounds__(256) void k_rope(
    float* __restrict__ buf, const int* __restrict__ pos, int nh) {
  int s = blockIdx.x;
  int hh = blockIdx.y*4 + (threadIdx.x >> 6);
  int d = threadIdx.x & 63;
  float p = (float)pos[s];
  // mimic numpy: pw = theta**(2d/128) in f32, inv = 1.0f/pw
  double ex = ((double)(2*d)/128.0) * 9.210340371976184; // log(10000)
  float pw = (float)exp(ex);
  float inv = 1.0f / pw;
  float ang = p * inv;
  float cs = cosf(ang), sn = sinf(ang);
  float* b = buf + (size_t)s*(nh*128) + hh*128 + d;
  float x1 = b[0], x2 = b[64];
  b[0]  = x1*cs - x2*sn;
  b[64] = x2*cs + x1*sn;
}

// ---------------- flash attention, fp16x2 split, causal GQA ----------------
__global__ __launch_bounds__(256) void k_attn(
    const float* __restrict__ q, const float* __restrict__ k,
    const float* __restrict__ v, float* __restrict__ o) {
  const int qt = blockIdx.x, h = blockIdx.y;
  const int tid = threadIdx.x, l = tid & 63, w = tid >> 6;
  const int qb = qt*64, qw = qb + w*16;
  const int kvh = h >> 2;

  __shared__ _Float16 kHi[32*128], kLo[32*128];
  __shared__ _Float16 vHi[128*32], vLo[128*32];  // transposed [d][kv]
  __shared__ _Float16 pHi[4][16*40], pLo[4][16*40];

  f16x8 qh[4], ql[4];
  {
    int qrow = qw + (l & 15);
    const float* qp = q + (size_t)qrow*2048 + h*128 + (l>>4)*8;
    #pragma unroll
    for (int c = 0; c < 4; ++c)
      #pragma unroll
      for (int j = 0; j < 8; ++j) {
        float x = qp[c*32 + j];
        _Float16 hh = (_Float16)x;
        qh[c][j] = hh; ql[c][j] = (_Float16)(x - (float)hh);
      }
  }

  float mrun[4], lrun[4];
  f32x4 oacc[8] = {};
  #pragma unroll
  for (int r = 0; r < 4; ++r) { mrun[r] = -1e30f; lrun[r] = 0.f; }

  const int srow = tid >> 3, sc = (tid & 7)*2;

  for (int kv0 = 0; kv0 <= qb + 32; kv0 += 32) {
    __syncthreads();
    { // stage K (row-major, XOR swizzle) and V (transposed, XOR swizzle)
      const float* kp = k + (size_t)(kv0 + srow)*512 + kvh*128 + sc*8;
      const float* vp = v + (size_t)(kv0 + srow)*512 + kvh*128 + sc*8;
      #pragma unroll
      for (int cc = 0; cc < 2; ++cc) {
        int c = sc + cc;
        H8 ph, pl;
        #pragma unroll
        for (int j = 0; j < 8; ++j) {
          float x = kp[cc*8 + j];
          _Float16 hh = (_Float16)x;
          ph.h[j] = hh; pl.h[j] = (_Float16)(x - (float)hh);
        }
        int di = srow*128 + (c ^ (srow & 7))*8;
        *(H8*)&kHi[di] = ph;
        *(H8*)&kLo[di] = pl;
        #pragma unroll
        for (int j = 0; j < 8; ++j) {
          float x = vp[cc*8 + j];
          _Float16 hh = (_Float16)x;
          _Float16 ll = (_Float16)(x - (float)hh);
          int d = c*8 + j;
          int vi = d*32 + (((srow>>3) ^ (d&3)))*8 + (srow & 7);
          vHi[vi] = hh; vLo[vi] = ll;
        }
      }
    }
    __syncthreads();
    if (kv0 <= qw + 15) {
      f32x4 s[2] = {};
      #pragma unroll
      for (int nt = 0; nt < 2; ++nt) {
        int krow = nt*16 + (l & 15);
        #pragma unroll
        for (int c = 0; c < 4; ++c) {
          int ch = (c*4 + (l>>4)) ^ (krow & 7);
          f16x8 bh = *(const f16x8*)&kHi[krow*128 + ch*8];
          f16x8 bl = *(const f16x8*)&kLo[krow*128 + ch*8];
          s[nt] = mfma16(qh[c], bh, s[nt]);
          s[nt] = mfma16(qh[c], bl, s[nt]);
          s[nt] = mfma16(ql[c], bh, s[nt]);
        }
      }
      const float SC = 0.08838834764831845f;
      float sv[2][4];
      #pragma unroll
      for (int nt = 0; nt < 2; ++nt)
        #pragma unroll
        for (int r = 0; r < 4; ++r) {
          float val = s[nt][r]*SC;
          int qg = qw + (l>>4)*4 + r;
          int kg = kv0 + nt*16 + (l & 15);
          sv[nt][r] = (kg > qg) ? -1e30f : val;
        }
      float tm[4];
      #pragma unroll
      for (int r = 0; r < 4; ++r) tm[r] = fmaxf(sv[0][r], sv[1][r]);
      #pragma unroll
      for (int mm = 1; mm < 16; mm <<= 1)
        #pragma unroll
        for (int r = 0; r < 4; ++r) tm[r] = fmaxf(tm[r], __shfl_xor(tm[r], mm));
      float alpha[4], rs[4];
      #pragma unroll
      for (int r = 0; r < 4; ++r) {
        float mn = fmaxf(mrun[r], tm[r]);
        alpha[r] = expf(mrun[r] - mn);
        mrun[r] = mn;
      }
      float pv[2][4];
      #pragma unroll
      for (int nt = 0; nt < 2; ++nt)
        #pragma unroll
        for (int r = 0; r < 4; ++r) pv[nt][r] = expf(sv[nt][r] - mrun[r]);
      #pragma unroll
      for (int r = 0; r < 4; ++r) rs[r] = pv[0][r] + pv[1][r];
      #pragma unroll
      for (int mm = 1; mm < 16; mm <<= 1)
        #pragma unroll
        for (int r = 0; r < 4; ++r) rs[r] += __shfl_xor(rs[r], mm);
      #pragma unroll
      for (int r = 0; r < 4; ++r) lrun[r] = lrun[r]*alpha[r] + rs[r];
      #pragma unroll
      for (int dt = 0; dt < 8; ++dt)
        #pragma unroll
        for (int r = 0; r < 4; ++r) oacc[dt][r] *= alpha[r];
      // P -> per-wave LDS (split), then read back as A-fragments
      #pragma unroll
      for (int nt = 0; nt < 2; ++nt)
        #pragma unroll
        for (int r = 0; r < 4; ++r) {
          float x = pv[nt][r];
          _Float16 hh = (_Float16)x;
          int qr = (l>>4)*4 + r, kc = nt*16 + (l & 15);
          pHi[w][qr*40 + kc] = hh;
          pLo[w][qr*40 + kc] = (_Float16)(x - (float)hh);
        }
      f16x8 pa = *(const f16x8*)&pHi[w][(l&15)*40 + (l>>4)*8];
      f16x8 pb = *(const f16x8*)&pLo[w][(l&15)*40 + (l>>4)*8];
      #pragma unroll
      for (int dt = 0; dt < 8; ++dt) {
        int d = dt*16 + (l & 15);
        int ch = ((l>>4) ^ (d & 3))*8;
        f16x8 vh = *(const f16x8*)&vHi[d*32 + ch];
        f16x8 vl = *(const f16x8*)&vLo[d*32 + ch];
        oacc[dt] = mfma16(pa, vh, oacc[dt]);
        oacc[dt] = mfma16(pa, vl, oacc[dt]);
        oacc[dt] = mfma16(pb, vh, oacc[dt]);
      }
    }
  }
  #pragma unroll
  for (int dt = 0; dt < 8; ++dt)
    #pragma unroll
    for (int r = 0; r < 4; ++r) {
      int qg = qw + (l>>4)*4 + r;
      o[(size_t)qg*2048 + h*128 + dt*16 + (l&15)] = oacc[dt][r] / lrun[r];
    }
}

// ---------------- post-attn RMSNorm + gate logits ----------------
__global__ __launch_bounds__(256) void k_postnorm_gate(
    const float* __restrict__ resid, const float* __restrict__ wln,
    const float* __restrict__ wg, _Float16* __restrict__ h2,
    float* __restrict__ logits) {
  __shared__ float red[4];
  __shared__ float red2[4][8];
  int row = blockIdx.x, tid = threadIdx.x;
  const float* xr = resid + (size_t)row*2048 + tid*8;
  float xs[8];
  *(float4*)&xs[0] = *(const float4*)xr;
  *(float4*)&xs[4] = *(const float4*)(xr + 4);
  float ss = 0.f;
  #pragma unroll
  for (int j = 0; j < 8; ++j) ss += xs[j]*xs[j];
  float tot = block_sum(ss, red, tid);
  float sc = 1.0f/sqrtf(tot*(1.0f/2048.0f) + 1e-5f);
  const float* wr = wln + tid*8;
  float hv[8];
  H8 ph;
  #pragma unroll
  for (int j = 0; j < 8; ++j) {
    hv[j] = xs[j]*sc*wr[j];
    ph.h[j] = (_Float16)hv[j];
  }
  *(H8*)(h2 + (size_t)row*2048 + tid*8) = ph;
  float lg[8] = {0,0,0,0,0,0,0,0};
  const float* wgp = wg + (size_t)tid*8*8;
  #pragma unroll
  for (int j = 0; j < 8; ++j)
    #pragma unroll
    for (int e = 0; e < 8; ++e) lg[e] += hv[j]*wgp[j*8 + e];
  #pragma unroll
  for (int mm = 1; mm < 64; mm <<= 1)
    #pragma unroll
    for (int e = 0; e < 8; ++e) lg[e] += __shfl_xor(lg[e], mm);
  if ((tid & 63) == 0)
    #pragma unroll
    for (int e = 0; e < 8; ++e) red2[tid>>6][e] = lg[e];
  __syncthreads();
  if (tid < 8)
    logits[(size_t)row*8 + tid] = red2[0][tid]+red2[1][tid]+red2[2][tid]+red2[3][tid];
}

// ---------------- routing: top-2, slot lists ----------------
__global__ __launch_bounds__(256) void k_route(
    const float* __restrict__ logits, int* __restrict__ counts,
    int* __restrict__ slot_tok, float* __restrict__ slot_w) {
  int t = blockIdx.x*256 + threadIdx.x;
  if (t >= 2048) return;
  float lg[8];
  #pragma unroll
  for (int e = 0; e < 8; ++e) lg[e] = logits[t*8 + e];
  int a = 0; float la = lg[0];
  #pragma unroll
  for (int e = 1; e < 8; ++e) if (lg[e] > la) { la = lg[e]; a = e; }
  int b = -1; float lb = -3e38f;
  #pragma unroll
  for (int e = 0; e < 8; ++e) if (e != a && lg[e] > lb) { lb = lg[e]; b = e; }
  float wa = 1.f/(1.f + expf(lb - la));
  float wb = 1.f - wa;
  int sa = atomicAdd(&counts[a], 1);
  slot_tok[a*2048 + sa] = t; slot_w[a*2048 + sa] = wa;
  int sb = atomicAdd(&counts[b], 1);
  slot_tok[b*2048 + sb] = t; slot_w[b*2048 + sb] = wb;
}

__global__ void k_scan(const int* __restrict__ counts, int* __restrict__ offs) {
  if (threadIdx.x == 0) {
    int o_ = 0;
    #pragma unroll
    for (int e = 0; e < 8; ++e) { offs[e] = o_; o_ += counts[e]; }
  }
}

// ---------------- MoE GEMM1: g = silu(A@w1)*(A@w3), gathered rows, fp16 ----------------
__global__ __launch_bounds__(256) void k_moe1(
    const _Float16* __restrict__ h2, const float* __restrict__ w1,
    const float* __restrict__ w3, const int* __restrict__ counts,
    const int* __restrict__ offs, const int* __restrict__ slot_tok,
    _Float16* __restrict__ g) {
  int bid = blockIdx.x;
  int e = bid >> 10, mt = (bid >> 6) & 15, nt = bid & 63;
  int cnt = counts[e];
  if (mt*128 >= cnt) return;
  const int tid = threadIdx.x, l = tid & 63, w = tid >> 6;
  const int wm = w >> 1, wn = w & 1;
  __shared__ _Float16 aT[128*32];
  __shared__ _Float16 b1[64*36], b3[64*36];
  const int rS = tid >> 1, khalf = tid & 1;
  int slot = mt*128 + rS;
  int tok = (slot < cnt) ? slot_tok[e*2048 + slot] : 0;
  const _Float16* arow = h2 + (size_t)tok*2048;
  const float* w1e = w1 + (size_t)e*2048*4096;
  const float* w3e = w3 + (size_t)e*2048*4096;
  const int bn = tid & 63, bkg = tid >> 6;
  f32x4 acc1[4][2] = {}, acc3[4][2] = {};
  for (int k0 = 0; k0 < 2048; k0 += 32) {
    __syncthreads();
    {
      const _Float16* ap = arow + k0 + khalf*16;
      int c0 = khalf*2;
      *(H8*)&aT[rS*32 + ((c0  )^(rS&3))*8] = *(const H8*)ap;
      *(H8*)&aT[rS*32 + ((c0+1)^(rS&3))*8] = *(const H8*)(ap + 8);
    }
    {
      const float* bp1 = w1e + (size_t)(k0 + bkg*8)*4096 + nt*64 + bn;
      const float* bp3 = w3e + (size_t)(k0 + bkg*8)*4096 + nt*64 + bn;
      float t1[8], t3[8];
      #pragma unroll
      for (int i = 0; i < 8; ++i) { t1[i] = bp1[(size_t)i*4096]; t3[i] = bp3[(size_t)i*4096]; }
      #pragma unroll
      for (int q_ = 0; q_ < 2; ++q_) {
        H4 p1, p3;
        #pragma unroll
        for (int j = 0; j < 4; ++j) { p1.h[j] = (_Float16)t1[q_*4+j]; p3.h[j] = (_Float16)t3[q_*4+j]; }
        int ei = bn*36 + bkg*8 + q_*4;
        *(H4*)&b1[ei] = p1;
        *(H4*)&b3[ei] = p3;
      }
    }
    __syncthreads();
    {
      const int kc = l >> 4;
      f16x8 a_[4];
      #pragma unroll
      for (int m = 0; m < 4; ++m) {
        int mr = wm*64 + m*16 + (l & 15);
        a_[m] = *(const f16x8*)&aT[mr*32 + (kc ^ (mr&3))*8];
      }
      #pragma unroll
      for (int n = 0; n < 2; ++n) {
        int nr = wn*32 + n*16 + (l & 15);
        f16x8 bb1 = frag_b36(b1, nr, kc);
        f16x8 bb3 = frag_b36(b3, nr, kc);
        #pragma unroll
        for (int m = 0; m < 4; ++m) {
          acc1[m][n] = mfma16(a_[m], bb1, acc1[m][n]);
          acc3[m][n] = mfma16(a_[m], bb3, acc3[m][n]);
        }
      }
    }
  }
  int ge = offs[e];
  #pragma unroll
  for (int m = 0; m < 4; ++m)
    #pragma unroll
    for (int n = 0; n < 2; ++n)
      #pragma unroll
      for (int r = 0; r < 4; ++r) {
        int srow2 = mt*128 + wm*64 + m*16 + (l>>4)*4 + r;
        if (srow2 < cnt) {
          float x1 = acc1[m][n][r], x3 = acc3[m][n][r];
          float gg = (x1/(1.f + expf(-x1)))*x3;
          int col = nt*64 + wn*32 + n*16 + (l&15);
          g[(size_t)(ge + srow2)*4096 + col] = (_Float16)gg;
        }
      }
}

// ---------------- MoE GEMM2: out[tok] += wgt * (g@w2), atomic scatter ----------------
__global__ __launch_bounds__(256) void k_moe2(
    const _Float16* __restrict__ g, const float* __restrict__ w2,
    const int* __restrict__ counts, const int* __restrict__ offs,
    const int* __restrict__ slot_tok, const float* __restrict__ slot_w,
    float* __restrict__ out) {
  int bid = blockIdx.x;
  int e = bid >> 8, mt = (bid >> 4) & 15, nt = bid & 15;
  int cnt = counts[e];
  if (mt*128 >= cnt) return;
  const int tid = threadIdx.x, l = tid & 63, w = tid >> 6;
  const int wm = w >> 1, wn = w & 1;
  __shared__ _Float16 aT[128*32];
  __shared__ _Float16 bT[128*36];
  const int rS = tid >> 1, khalf = tid & 1;
  int ge = offs[e];
  int slot = mt*128 + rS;
  const _Float16* arow = g + (size_t)(ge + (slot < cnt ? slot : 0))*4096;
  const float* w2e = w2 + (size_t)e*4096*2048;
  const int bn = tid & 127, bkg = tid >> 7;
  f32x4 acc[4][4] = {};
  for (int k0 = 0; k0 < 4096; k0 += 32) {
    __syncthreads();
    {
      const _Float16* ap = arow + k0 + khalf*16;
      int c0 = khalf*2;
      *(H8*)&aT[rS*32 + ((c0  )^(rS&3))*8] = *(const H8*)ap;
      *(H8*)&aT[rS*32 + ((c0+1)^(rS&3))*8] = *(const H8*)(ap + 8);
    }
    {
      const float* bp = w2e + (size_t)(k0 + bkg*16)*2048 + nt*128 + bn;
      float tv[16];
      #pragma unroll
      for (int i = 0; i < 16; ++i) tv[i] = bp[(size_t)i*2048];
      #pragma unroll
      for (int q_ = 0; q_ < 4; ++q_) {
        H4 ph;
        #pragma unroll
        for (int j = 0; j < 4; ++j) ph.h[j] = (_Float16)tv[q_*4+j];
        *(H4*)&bT[bn*36 + bkg*16 + q_*4] = ph;
      }
    }
    __syncthreads();
    {
      const int kc = l >> 4;
      f16x8 a_[4];
      #pragma unroll
      for (int m = 0; m < 4; ++m) {
        int mr = wm*64 + m*16 + (l&15);
        a_[m] = *(const f16x8*)&aT[mr*32 + (kc ^ (mr&3))*8];
      }
      #pragma unroll
      for (int n = 0; n < 4; ++n) {
        f16x8 bb = frag_b36(bT, wn*64 + n*16 + (l&15), kc);
        #pragma unroll
        for (int m = 0; m < 4; ++m) acc[m][n] = mfma16(a_[m], bb, acc[m][n]);
      }
    }
  }
  #pragma unroll
  for (int m = 0; m < 4; ++m)
    #pragma unroll
    for (int r = 0; r < 4; ++r) {
      int srow2 = mt*128 + wm*64 + m*16 + (l>>4)*4 + r;
      if (srow2 < cnt) {
        int tok = slot_tok[e*2048 + srow2];
        float wt = slot_w[e*2048 + srow2];
        #pragma unroll
        for (int n = 0; n < 4; ++n) {
          int col = nt*128 + wn*64 + n*16 + (l&15);
          atomicAdd(&out[(size_t)tok*2048 + col], wt*acc[m][n][r]);
        }
      }
    }
}

extern "C" void kernel_launch(void* const* d_in, const int* in_sizes, int n_in,
                              void* d_out, int out_size, void* d_ws, size_t ws_size,
                              hipStream_t stream) {
  const int*   positions = (const int*)d_in[0];
  const float* x   = (const float*)d_in[1];
  const float* wq  = (const float*)d_in[2];
  const float* wk  = (const float*)d_in[3];
  const float* wv  = (const float*)d_in[4];
  const float* wo  = (const float*)d_in[5];
  const float* wg  = (const float*)d_in[6];
  const float* w1  = (const float*)d_in[7];
  const float* w2  = (const float*)d_in[8];
  const float* w3  = (const float*)d_in[9];
  const float* ln_in   = (const float*)d_in[10];
  const float* ln_post = (const float*)d_in[11];

  float* moe_out   = (float*)d_out;
  float* resid_out = (float*)d_out + (size_t)4194304;

  char* ws = (char*)d_ws;
  _Float16* h_hi   = (_Float16*)(ws);
  _Float16* h_lo   = (_Float16*)(ws + 8388608);
  float*    qbuf   = (float*)(ws + 16777216);
  float*    kbuf   = (float*)(ws + 33554432);
  float*    vbuf   = (float*)(ws + 37748736);
  float*    attn   = (float*)(ws + 41943040);
  _Float16* h2     = (_Float16*)(ws + 58720256);
  float*    logits = (float*)(ws + 67108864);
  int*      counts = (int*)(ws + 67174400);
  int*      offs   = (int*)(ws + 67174656);
  int*      slot_tok = (int*)(ws + 67174912);
  float*    slot_w   = (float*)(ws + 67240448);
  _Float16* gbuf   = (_Float16*)ws;   // aliases h_hi/h_lo/qbuf (dead by MoE time)

  hipMemsetAsync(moe_out, 0, (size_t)4194304*4, stream);
  hipMemsetAsync(counts, 0, 32, stream);

  k_rmsnorm_split<<<2048, 256, 0, stream>>>(x, ln_in, h_hi, h_lo);
  k_gemm<0,false><<<dim3(16,16), 256, 0, stream>>>(h_hi, h_lo, wq, 2048, 2048, qbuf, nullptr, nullptr);
  k_gemm<0,false><<<dim3(4,16),  256, 0, stream>>>(h_hi, h_lo, wk,  512, 2048, kbuf, nullptr, nullptr);
  k_gemm<0,false><<<dim3(4,16),  256, 0, stream>>>(h_hi, h_lo, wv,  512, 2048, vbuf, nullptr, nullptr);
  k_rope<<<dim3(2048,4), 256, 0, stream>>>(qbuf, positions, 16);
  k_rope<<<dim3(2048,1), 256, 0, stream>>>(kbuf, positions, 4);
  k_attn<<<dim3(32,16), 256, 0, stream>>>(qbuf, kbuf, vbuf, attn);
  k_gemm<1,true><<<dim3(16,16), 256, 0, stream>>>(attn, nullptr, wo, 2048, 2048, nullptr, x, resid_out);
  k_postnorm_gate<<<2048, 256, 0, stream>>>(resid_out, ln_post, wg, h2, logits);
  k_route<<<8, 256, 0, stream>>>(logits, counts, slot_tok, slot_w);
  k_scan<<<1, 64, 0, stream>>>(counts, offs);
  k_moe1<<<8192, 256, 0, stream>>>(h2, w1, w3, counts, offs, slot_tok, gbuf);
  k_moe2<<<2048, 256, 0, stream>>>(gbuf, w2, counts, offs, slot_tok, slot_w, moe_out);
}